// Round 1
// baseline (118.536 us; speedup 1.0000x reference)
//
#include <hip/hip_runtime.h>

// CrossInnerProductWithBuyer: per batch b,
//   out[b, 0:10]  =  dot(windows[b,w,:], center[b,:])
//   out[b,10:74]  = -dot(neg[b,n,:],     center[b,:])
//   out[b,   74]  =  dot(center[b,:],    buy[b,:])
// B=16384, W=10, N=64, E=128, all fp32. Memory-bound (~421 MB traffic).
//
// One wave (64 lanes) per batch. Each wave-load of float4 covers TWO
// consecutive 128-float rows (lanes 0-31 -> row 2r, lanes 32-63 -> row 2r+1),
// fully coalesced 1KB transactions. 5-step shfl_xor reduce within each
// 32-lane half; lanes 0 and 32 write the two results.

__global__ __launch_bounds__(256) void cross_inner_kernel(
    const float* __restrict__ center,   // [B,128]
    const float* __restrict__ windows,  // [B,10,128]
    const float* __restrict__ neg,      // [B,64,128]
    const float* __restrict__ buy,      // [B,128]
    float* __restrict__ out,            // [B,75]
    int B)
{
    const int wave = threadIdx.x >> 6;          // wave within block (0..3)
    const int lane = threadIdx.x & 63;
    const int b = blockIdx.x * 4 + wave;
    if (b >= B) return;

    const int half = lane >> 5;                 // 0: even row, 1: odd row
    const int k    = lane & 31;                 // lane within half

    // center quad: element range [k*4, k*4+3]; same for both halves
    const float4 c4 = *reinterpret_cast<const float4*>(
        center + (size_t)b * 128 + k * 4);

    float* outb = out + (size_t)b * 75;

    // ---- windows: 10 rows = 5 pairs ----
    const float* wb = windows + (size_t)b * 10 * 128;
    #pragma unroll
    for (int r = 0; r < 5; ++r) {
        float4 v = *reinterpret_cast<const float4*>(wb + r * 256 + lane * 4);
        float p = v.x * c4.x + v.y * c4.y + v.z * c4.z + v.w * c4.w;
        #pragma unroll
        for (int m = 1; m <= 16; m <<= 1) p += __shfl_xor(p, m, 64);
        if (k == 0) outb[2 * r + half] = p;
    }

    // ---- neg: 64 rows = 32 pairs (negated) ----
    const float* nb = neg + (size_t)b * 64 * 128;
    #pragma unroll
    for (int r = 0; r < 32; ++r) {
        float4 v = *reinterpret_cast<const float4*>(nb + r * 256 + lane * 4);
        float p = v.x * c4.x + v.y * c4.y + v.z * c4.z + v.w * c4.w;
        #pragma unroll
        for (int m = 1; m <= 16; m <<= 1) p += __shfl_xor(p, m, 64);
        if (k == 0) outb[10 + 2 * r + half] = -p;
    }

    // ---- buy: 1 row; both halves compute the same full-row sum ----
    const float4 bv = *reinterpret_cast<const float4*>(
        buy + (size_t)b * 128 + k * 4);
    float p = bv.x * c4.x + bv.y * c4.y + bv.z * c4.z + bv.w * c4.w;
    #pragma unroll
    for (int m = 1; m <= 16; m <<= 1) p += __shfl_xor(p, m, 64);
    if (lane == 0) outb[74] = p;
}

extern "C" void kernel_launch(void* const* d_in, const int* in_sizes, int n_in,
                              void* d_out, int out_size, void* d_ws, size_t ws_size,
                              hipStream_t stream) {
    const float* center  = (const float*)d_in[0];
    const float* windows = (const float*)d_in[1];
    const float* neg     = (const float*)d_in[2];
    const float* buy     = (const float*)d_in[3];
    float* out = (float*)d_out;

    const int B = in_sizes[0] / 128;            // 16384
    const int blocks = (B + 3) / 4;             // 4 waves (batches) per block

    cross_inner_kernel<<<blocks, 256, 0, stream>>>(center, windows, neg, buy, out, B);
}

// Round 2
// 105.789 us; speedup vs baseline: 1.1205x; 1.1205x over previous
//
#include <hip/hip_runtime.h>

// CrossInnerProductWithBuyer: per batch b (B=16384, W=10, N=64, E=128, fp32):
//   out[b, 0:10]  =  dot(windows[b,w,:], center[b,:])
//   out[b,10:74]  = -dot(neg[b,n,:],     center[b,:])
//   out[b,   74]  =  dot(center[b,:],    buy[b,:])
//
// Memory-bound: 637.5 MB read + 4.9 MB write, floor ~102 us @ 6.3 TB/s.
//
// One wave per batch. Lane i loads float4 -> one wave-load covers TWO
// consecutive 128-float rows (lanes 0-31 row 2r, lanes 32-63 row 2r+1).
// Rows are processed in chunks of 8 row-pairs; the 8 per-lane partials are
// reduced SIMULTANEOUSLY with a 3-stage butterfly tree (select+shfl+add,
// value index bits follow lane index bits) + 2 broadcast stages, so after
// 7 shuffles lane k (in each 32-lane half) holds the full sum of row-pair
// (k&7) -> one coalesced 16-float store per chunk. 5x fewer DS-swizzle ops
// and 38 divergent stores -> 5 coalesced stores vs the round-1 kernel.
// All bulk loads are nontemporal (stream-once data, 637 MB >> L3).

typedef float f32x4 __attribute__((ext_vector_type(4)));

__device__ __forceinline__ f32x4 ntload4(const float* p) {
    return __builtin_nontemporal_load(reinterpret_cast<const f32x4*>(p));
}

__global__ __launch_bounds__(256) void cross_inner_kernel(
    const float* __restrict__ center,   // [B,128]
    const float* __restrict__ windows,  // [B,10,128]
    const float* __restrict__ neg,      // [B,64,128]
    const float* __restrict__ buy,      // [B,128]
    float* __restrict__ out,            // [B,75]
    int B)
{
    const int wave = threadIdx.x >> 6;
    const int lane = threadIdx.x & 63;
    const int b = blockIdx.x * 4 + wave;
    if (b >= B) return;

    const int half = lane >> 5;   // which row of the pair this lane covers
    const int k    = lane & 31;   // lane within 32-lane half

    const f32x4 c4 = ntload4(center + (size_t)b * 128 + k * 4);

    float* outb = out + (size_t)b * 75;
    const float* wb = windows + (size_t)b * 10 * 128 + lane * 4;
    const float* nb = neg     + (size_t)b * 64 * 128 + lane * 4;

#define DOT4(v) ((v).x * c4.x + (v).y * c4.y + (v).z * c4.z + (v).w * c4.w)

    // 8-value butterfly tree within each 32-lane half.
    // After this, every lane holds the full 32-lane sum of value index (k&7).
#define TREE8(v0,v1,v2,v3,v4,v5,v6,v7,res)                                   \
    {                                                                        \
        float a0 = (k & 1) ? v1 : v0, g0 = (k & 1) ? v0 : v1;                \
        float a1 = (k & 1) ? v3 : v2, g1 = (k & 1) ? v2 : v3;                \
        float a2 = (k & 1) ? v5 : v4, g2 = (k & 1) ? v4 : v5;                \
        float a3 = (k & 1) ? v7 : v6, g3 = (k & 1) ? v6 : v7;                \
        a0 += __shfl_xor(g0, 1, 64);                                         \
        a1 += __shfl_xor(g1, 1, 64);                                         \
        a2 += __shfl_xor(g2, 1, 64);                                         \
        a3 += __shfl_xor(g3, 1, 64);                                         \
        float b0 = (k & 2) ? a1 : a0, h0 = (k & 2) ? a0 : a1;                \
        float b1 = (k & 2) ? a3 : a2, h1 = (k & 2) ? a2 : a3;                \
        b0 += __shfl_xor(h0, 2, 64);                                         \
        b1 += __shfl_xor(h1, 2, 64);                                         \
        float c0 = (k & 4) ? b1 : b0, i0 = (k & 4) ? b0 : b1;                \
        c0 += __shfl_xor(i0, 4, 64);                                         \
        c0 += __shfl_xor(c0, 8, 64);                                         \
        c0 += __shfl_xor(c0, 16, 64);                                        \
        res = c0;                                                            \
    }

    // ---- windows (5 row-pairs) + buy (1 full row per half) ----
    {
        f32x4 t0 = ntload4(wb + 0 * 256);
        f32x4 t1 = ntload4(wb + 1 * 256);
        f32x4 t2 = ntload4(wb + 2 * 256);
        f32x4 t3 = ntload4(wb + 3 * 256);
        f32x4 t4 = ntload4(wb + 4 * 256);
        f32x4 tb = ntload4(buy + (size_t)b * 128 + k * 4);
        float v0 = DOT4(t0), v1 = DOT4(t1), v2 = DOT4(t2);
        float v3 = DOT4(t3), v4 = DOT4(t4), v5 = DOT4(tb);
        float z = 0.0f, r;
        TREE8(v0, v1, v2, v3, v4, v5, z, z, r);
        // lane (half,k): value (k&7); windows pair i -> row 2i+half;
        // value 5 = buy dot (identical in both halves).
        if (k < 5)               outb[2 * k + half] = r;
        if (k == 5 && half == 0) outb[74] = r;
    }

    // ---- neg: 64 rows = 32 pairs = 4 chunks of 8 pairs ----
    #pragma unroll
    for (int c = 0; c < 4; ++c) {
        const float* base = nb + c * 8 * 256;
        f32x4 t0 = ntload4(base + 0 * 256);
        f32x4 t1 = ntload4(base + 1 * 256);
        f32x4 t2 = ntload4(base + 2 * 256);
        f32x4 t3 = ntload4(base + 3 * 256);
        f32x4 t4 = ntload4(base + 4 * 256);
        f32x4 t5 = ntload4(base + 5 * 256);
        f32x4 t6 = ntload4(base + 6 * 256);
        f32x4 t7 = ntload4(base + 7 * 256);
        float v0 = DOT4(t0), v1 = DOT4(t1), v2 = DOT4(t2), v3 = DOT4(t3);
        float v4 = DOT4(t4), v5 = DOT4(t5), v6 = DOT4(t6), v7 = DOT4(t7);
        float r;
        TREE8(v0, v1, v2, v3, v4, v5, v6, v7, r);
        // lane (half,k) holds pair (8c + (k&7)) -> row 2*(8c+k)+half
        if (k < 8) outb[10 + 16 * c + 2 * k + half] = -r;
    }

#undef DOT4
#undef TREE8
}

extern "C" void kernel_launch(void* const* d_in, const int* in_sizes, int n_in,
                              void* d_out, int out_size, void* d_ws, size_t ws_size,
                              hipStream_t stream) {
    const float* center  = (const float*)d_in[0];
    const float* windows = (const float*)d_in[1];
    const float* neg     = (const float*)d_in[2];
    const float* buy     = (const float*)d_in[3];
    float* out = (float*)d_out;

    const int B = in_sizes[0] / 128;            // 16384
    const int blocks = (B + 3) / 4;             // 4 waves (batches) per block

    cross_inner_kernel<<<blocks, 256, 0, stream>>>(center, windows, neg, buy, out, B);
}